// Round 13
// baseline (374.764 us; speedup 1.0000x reference)
//
#include <hip/hip_runtime.h>
#include <math.h>

typedef short bf16x8 __attribute__((ext_vector_type(8)));
typedef float f32x4  __attribute__((ext_vector_type(4)));

#define NPOS 32768
#define LOG2E 1.4426950408889634f

// ---- workspace byte offsets ----
#define OFF_AHI   100663296u    // short [32768][256]   16777216
#define OFF_ATTN  134217728u    // short [32768][256]   16777216
#define OFF_BIAST 150994944u    // float [8][256][256]   2097152  (layout [h][j][i], LOG2E-prescaled)
#define OFF_WHI   153354240u    // short [1024][256]      524288
#define OFF_W2P   154402816u    // short [256][256]       131072
#define OFF_GBP   154533888u    // float [256]              1024

__device__ __forceinline__ short f2bf(float x) {
    unsigned int u = __float_as_uint(x);
    unsigned int r = (u + 0x7FFFu + ((u >> 16) & 1u)) >> 16;
    return (short)r;
}
__device__ __forceinline__ float bf2f(short s) {
    return __uint_as_float(((unsigned int)(unsigned short)s) << 16);
}
__device__ __forceinline__ void async_copy16(const void* g, void* l) {
    __builtin_amdgcn_global_load_lds(
        (const __attribute__((address_space(1))) unsigned int*)g,
        (__attribute__((address_space(3))) unsigned int*)l, 16, 0, 0);
}

// ---------------- kernel 1: fused prep (ln_cast | castw | bias2) ----------------
#define PREP_LN   8192
#define PREP_CW   9473
__global__ __launch_bounds__(256) void k_prep(
    const float* __restrict__ x, const float* __restrict__ nw, const float* __restrict__ nb,
    const float* __restrict__ qkvw, const float* __restrict__ gatew,
    const float* __restrict__ gateb, const float* __restrict__ finalw,
    const float* __restrict__ x2d, const float* __restrict__ x2dw,
    short* __restrict__ Ahi, short* __restrict__ Whi, short* __restrict__ W2p,
    float* __restrict__ gbp, float* __restrict__ biasT) {
    __shared__ float xs[64][132];
    __shared__ float ws[8][132];
    const int bid = blockIdx.x;
    const int t = threadIdx.x;

    if (bid < PREP_LN) {                       // ---- layernorm + cast ----
        int wid = (bid * 256 + t) >> 6;
        int lane = t & 63;
        const float4 v = ((const float4*)(x + (size_t)wid * 256))[lane];
        float s  = v.x + v.y + v.z + v.w;
        float ss = v.x*v.x + v.y*v.y + v.z*v.z + v.w*v.w;
        #pragma unroll
        for (int o = 32; o; o >>= 1) {
            s  += __shfl_xor(s,  o, 64);
            ss += __shfl_xor(ss, o, 64);
        }
        float mu  = s * (1.0f / 256);
        float var = ss * (1.0f / 256) - mu * mu;
        float rs  = rsqrtf(var + 1e-5f);
        const float4 wv = ((const float4*)nw)[lane];
        const float4 bv = ((const float4*)nb)[lane];
        float y[4] = {(v.x - mu) * rs * wv.x + bv.x, (v.y - mu) * rs * wv.y + bv.y,
                      (v.z - mu) * rs * wv.z + bv.z, (v.w - mu) * rs * wv.w + bv.w};
        short h4[4];
        #pragma unroll
        for (int i = 0; i < 4; ++i) h4[i] = f2bf(y[i]);
        *(short4*)(Ahi + (size_t)wid * 256 + lane * 4) = *(short4*)h4;
    } else if (bid < PREP_CW) {                // ---- weight permute + cast ----
        int r = bid - PREP_LN;
        if (r < 1024) {
            int which = r >> 8, h = (r >> 5) & 7, c = r & 31;
            const float* src = (which < 3) ? qkvw + (size_t)(c * 24 + which * 8 + h) * 256
                                           : gatew + (size_t)(c * 8 + h) * 256;
            Whi[(size_t)r * 256 + t] = f2bf(src[t]);
        } else if (r < 1280) {
            int o = r - 1024;
            int h = t >> 5, c = t & 31;
            W2p[(size_t)o * 256 + t] = f2bf(finalw[(size_t)o * 256 + c * 8 + h]);
        } else {
            int h = t >> 5, c = t & 31;
            gbp[t] = gateb[c * 8 + h];
        }
    } else {                                   // ---- pair bias (layout [h][j][i]) ----
        const int wid0 = (bid - PREP_CW) * 64;
        #pragma unroll
        for (int r = 0; r < 8; ++r) {
            int g = r * 256 + t;
            int row = g >> 5, c4 = g & 31;
            float4 v = *(const float4*)(x2d + (size_t)(wid0 + row) * 128 + c4 * 4);
            *(float4*)&xs[row][c4 * 4] = v;
        }
        {
            int h = t >> 5, c4 = t & 31;
            *(float4*)&ws[h][c4 * 4] = *(const float4*)(x2dw + h * 128 + c4 * 4);
        }
        __syncthreads();
        const float f = 0.17677669529663687f * LOG2E;   // prescaled for exp2 softmax
        const int i = wid0 >> 8;
        #pragma unroll
        for (int kk = 0; kk < 2; ++kk) {
            int o = t + kk * 256;
            int row = o >> 3, h = o & 7;
            float acc = 0.f;
            #pragma unroll
            for (int c4 = 0; c4 < 32; ++c4) {
                float4 xv = *(const float4*)&xs[row][c4 * 4];
                float4 wv = *(const float4*)&ws[h][c4 * 4];
                acc += xv.x * wv.x + xv.y * wv.y + xv.z * wv.z + xv.w * wv.w;
            }
            int j = (wid0 & 255) + row;
            biasT[(((h * 256 + j)) << 8) + i] = acc * f;
        }
    }
}

// ---------------- kernel 2: FUSED qkv-gemm + attention per (m,h) ----------------
// Phase 1: C[256x128] = A[m-panel] @ W[h-cols] (bit-identical MFMA order).
// Q relays through per-wave Pl scratch (same addressing as the P relay);
// gate stays in 8 packed regs and relays through Pl after the j0 loop.
// LDS arena = max(phase1 48K, phase2 Khi+VT+Pl 43.5K) = 49152 B -> 3 blocks/CU.
__global__ __launch_bounds__(512, 6) void k_fused(
    const short* __restrict__ Ahi, const short* __restrict__ Whi,
    const float* __restrict__ gbp, const float* __restrict__ biasT,
    short* __restrict__ attnB) {
    __shared__ __align__(16) short smem[24576];   // 49152 B
    short* As  = smem;              // [256][64]  (phase 1, 16384 shorts)
    short* Ws  = smem + 16384;      // [128][64]  (phase 1, 8192 shorts)
    short* Khi = smem;              // [256][32] swizzled (phase 2)
    short* VT  = smem + 8192;       // [32][264]  (8448 shorts)
    short* Pl  = smem + 16640;      // [8][16][40] per-wave scratch (5120 shorts)

    const int mh = blockIdx.x;
    const int h = mh >> 7, m = mh & 127;       // h-major: A-panel sharers on same XCD
    const int t = threadIdx.x;
    const int wave = t >> 6, lane = t & 63, ln15 = lane & 15, quad = lane >> 4;
    const int i0 = wave * 32;

    f32x4 acc[2][8];
    #pragma unroll
    for (int a = 0; a < 2; ++a)
        #pragma unroll
        for (int b = 0; b < 8; ++b) acc[a][b] = (f32x4){0.f, 0.f, 0.f, 0.f};

    // ---- phase 1: GEMM ----
    for (int k0 = 0; k0 < 256; k0 += 64) {
        #pragma unroll
        for (int r = 0; r < 4; ++r) {          // A: 256 rows x 64
            int g = r * 512 + t;
            int row = g >> 3, cs = g & 7;
            int colg = cs ^ (row & 7);
            async_copy16(Ahi + (size_t)(m * 256 + row) * 256 + k0 + colg * 8, &As[g * 8]);
        }
        #pragma unroll
        for (int r = 0; r < 2; ++r) {          // W: 128 rows x 64 (q,k,v,g for head h)
            int g = r * 512 + t;
            int row = g >> 3, cs = g & 7;
            int colg = cs ^ (row & 7);
            int nrow = (row >> 5) * 256 + h * 32 + (row & 31);
            async_copy16(Whi + (size_t)nrow * 256 + k0 + colg * 8, &Ws[g * 8]);
        }
        __syncthreads();
        #pragma unroll
        for (int kc = 0; kc < 2; ++kc) {
            bf16x8 af[2], bfr[8];
            #pragma unroll
            for (int it = 0; it < 2; ++it) {
                int rowa = i0 + it * 16 + ln15;
                int c8a = (kc * 4 + quad) ^ (rowa & 7);
                af[it] = *(const bf16x8*)&As[rowa * 64 + c8a * 8];
            }
            #pragma unroll
            for (int nt = 0; nt < 8; ++nt) {
                int rowb = nt * 16 + ln15;
                int c8b = (kc * 4 + quad) ^ (rowb & 7);
                bfr[nt] = *(const bf16x8*)&Ws[rowb * 64 + c8b * 8];
            }
            #pragma unroll
            for (int it = 0; it < 2; ++it)
                #pragma unroll
                for (int nt = 0; nt < 8; ++nt)
                    acc[it][nt] = __builtin_amdgcn_mfma_f32_16x16x32_bf16(
                        bfr[nt], af[it], acc[it][nt], 0, 0, 0);
        }
        __syncthreads();                        // also guards the overlay below
    }

    // ---- epilogue: C -> {Khi,VT} LDS; Q via per-wave Pl relay; gate -> regs ----
    unsigned gpk[2][4];                         // [it][w0,w1 (cols q*4) | w0,w1 (16+q*4)]
    bf16x8 qhi[2];
    short* plrow = &Pl[(wave * 16 + ln15) * 40];
    #pragma unroll
    for (int it = 0; it < 2; ++it) {
        int j = i0 + it * 16 + ln15;
        int sw = j & 3;
        #pragma unroll
        for (int nt = 0; nt < 8; ++nt) {
            int which = nt >> 1;
            int cloc0 = (nt & 1) * 16 + quad * 4;
            float v0 = acc[it][nt][0], v1 = acc[it][nt][1];
            float v2 = acc[it][nt][2], v3 = acc[it][nt][3];
            if (which == 3) {
                const float4 gb = *(const float4*)&gbp[h * 32 + cloc0];
                v0 = 1.0f / (1.0f + __expf(-(v0 + gb.x)));
                v1 = 1.0f / (1.0f + __expf(-(v1 + gb.y)));
                v2 = 1.0f / (1.0f + __expf(-(v2 + gb.z)));
                v3 = 1.0f / (1.0f + __expf(-(v3 + gb.w)));
            }
            short s0 = f2bf(v0), s1 = f2bf(v1), s2 = f2bf(v2), s3 = f2bf(v3);
            if (which == 2) {                   // V transposed, scalar stores
                VT[(cloc0 + 0) * 264 + j] = s0;
                VT[(cloc0 + 1) * 264 + j] = s1;
                VT[(cloc0 + 2) * 264 + j] = s2;
                VT[(cloc0 + 3) * 264 + j] = s3;
            } else {
                unsigned w0 = (unsigned)(unsigned short)s0 | ((unsigned)(unsigned short)s1 << 16);
                unsigned w1 = (unsigned)(unsigned short)s2 | ((unsigned)(unsigned short)s3 << 16);
                if (which == 0) {               // Q -> per-wave Pl relay
                    *(uint2*)&plrow[cloc0] = make_uint2(w0, w1);
                } else if (which == 1) {        // K -> Khi (swizzled, cross-wave)
                    int cg = cloc0 >> 3, off = cloc0 & 7;
                    *(uint2*)&Khi[j * 32 + (cg ^ sw) * 8 + off] = make_uint2(w0, w1);
                } else {                        // gate -> registers
                    gpk[it][(nt & 1) * 2]     = w0;
                    gpk[it][(nt & 1) * 2 + 1] = w1;
                }
            }
        }
        qhi[it] = *(const bf16x8*)&plrow[quad * 8];   // wave-local, in-order LDS
    }
    __syncthreads();

    // ---- phase 2: attention (exp2-domain softmax) ----
    float lacc[2] = {0.f, 0.f};
    f32x4 Oacc[2][2];
    #pragma unroll
    for (int a = 0; a < 2; ++a) {
        Oacc[a][0] = (f32x4){0.f, 0.f, 0.f, 0.f};
        Oacc[a][1] = (f32x4){0.f, 0.f, 0.f, 0.f};
    }
    const float* bp = biasT + (size_t)h * 65536;   // [j][i], LOG2E-prescaled

    for (int j0 = 0; j0 < 256; j0 += 32) {
        bf16x8 kfh[2], vf[2];
        #pragma unroll
        for (int jt = 0; jt < 2; ++jt) {
            int j = j0 + jt * 16 + ln15;
            int cs = quad ^ (j & 3);
            kfh[jt] = *(const bf16x8*)&Khi[j * 32 + cs * 8];
        }
        #pragma unroll
        for (int ct = 0; ct < 2; ++ct) {
            int c = ct * 16 + ln15;
            vf[ct] = *(const bf16x8*)&VT[c * 264 + j0 + quad * 8];
        }
        #pragma unroll
        for (int it = 0; it < 2; ++it) {
            int i = i0 + it * 16 + ln15;
            float b0[4], b1[4];
            #pragma unroll
            for (int r = 0; r < 4; ++r) {
                b0[r] = bp[(j0 + quad * 4 + r) * 256 + i];
                b1[r] = bp[(j0 + 16 + quad * 4 + r) * 256 + i];
            }
            f32x4 s0 = (f32x4){0.f, 0.f, 0.f, 0.f};
            f32x4 s1 = (f32x4){0.f, 0.f, 0.f, 0.f};
            s0 = __builtin_amdgcn_mfma_f32_16x16x32_bf16(kfh[0], qhi[it], s0, 0, 0, 0);
            s1 = __builtin_amdgcn_mfma_f32_16x16x32_bf16(kfh[1], qhi[it], s1, 0, 0, 0);
            // unnormalized softmax in exp2 domain: p = 2^(s*log2e + b_pre)
            float p[8], ps = 0.f;
            #pragma unroll
            for (int r = 0; r < 4; ++r) {
                p[r] = __builtin_amdgcn_exp2f(fmaf(s0[r], LOG2E, b0[r]));
                ps += p[r];
            }
            #pragma unroll
            for (int r = 0; r < 4; ++r) {
                p[4 + r] = __builtin_amdgcn_exp2f(fmaf(s1[r], LOG2E, b1[r]));
                ps += p[4 + r];
            }
            lacc[it] += ps;
            unsigned long long pw0 =
                  (unsigned long long)(unsigned short)f2bf(p[0])
                | ((unsigned long long)(unsigned short)f2bf(p[1]) << 16)
                | ((unsigned long long)(unsigned short)f2bf(p[2]) << 32)
                | ((unsigned long long)(unsigned short)f2bf(p[3]) << 48);
            unsigned long long pw1 =
                  (unsigned long long)(unsigned short)f2bf(p[4])
                | ((unsigned long long)(unsigned short)f2bf(p[5]) << 16)
                | ((unsigned long long)(unsigned short)f2bf(p[6]) << 32)
                | ((unsigned long long)(unsigned short)f2bf(p[7]) << 48);
            *(unsigned long long*)&plrow[quad * 4]      = pw0;
            *(unsigned long long*)&plrow[16 + quad * 4] = pw1;
            bf16x8 pf = *(const bf16x8*)&plrow[quad * 8];
            Oacc[it][0] = __builtin_amdgcn_mfma_f32_16x16x32_bf16(pf, vf[0], Oacc[it][0], 0, 0, 0);
            Oacc[it][1] = __builtin_amdgcn_mfma_f32_16x16x32_bf16(pf, vf[1], Oacc[it][1], 0, 0, 0);
        }
    }
    #pragma unroll
    for (int it = 0; it < 2; ++it) {
        // gate relay through per-wave Pl (same addressing as P relay)
        *(uint2*)&plrow[quad * 4]      = make_uint2(gpk[it][0], gpk[it][1]);
        *(uint2*)&plrow[16 + quad * 4] = make_uint2(gpk[it][2], gpk[it][3]);
        float l = lacc[it];
        l += __shfl_xor(l, 16, 64);
        l += __shfl_xor(l, 32, 64);
        float inv = 1.0f / l;
        float invr[4];
        #pragma unroll
        for (int r = 0; r < 4; ++r) invr[r] = __shfl(inv, quad * 4 + r, 16);
        #pragma unroll
        for (int ct = 0; ct < 2; ++ct) {
            int c = ct * 16 + ln15;
            #pragma unroll
            for (int r = 0; r < 4; ++r) {
                int i = i0 + it * 16 + quad * 4 + r;
                float g = bf2f(Pl[(wave * 16 + quad * 4 + r) * 40 + ct * 16 + ln15]);
                float val = Oacc[it][ct][r] * invr[r] * g;
                attnB[(size_t)(m * 256 + i) * 256 + h * 32 + c] = f2bf(val);
            }
        }
    }
}

// ---------------- kernel 3: MFMA GEMM2, single-buffer, transposed-frag epilogue ----------------
__global__ __launch_bounds__(256) void k_gemm2m(
    const short* __restrict__ A, const short* __restrict__ W2p,
    const float* __restrict__ fb, float* __restrict__ out) {
    __shared__ short As[128 * 64];
    __shared__ short Bs[128 * 64];
    const int t = threadIdx.x;
    const int wave = t >> 6, lane = t & 63, ln15 = lane & 15, quad = lane >> 4;
    const int posBase = blockIdx.x * 128;
    const int nb = blockIdx.y;
    const int i0w = (wave & 1) * 64, n0w = (wave >> 1) * 64;

    f32x4 acc[4][4];
    #pragma unroll
    for (int a = 0; a < 4; ++a)
        #pragma unroll
        for (int b = 0; b < 4; ++b) acc[a][b] = (f32x4){0.f, 0.f, 0.f, 0.f};

    for (int k0 = 0; k0 < 256; k0 += 64) {
        #pragma unroll
        for (int r = 0; r < 4; ++r) {
            int g = r * 256 + t;
            int row = g >> 3, cs = g & 7;
            int colg = cs ^ (row & 7);
            const short* ga = A + (size_t)(posBase + row) * 256 + k0 + colg * 8;
            async_copy16(ga, &As[(r * 256 + wave * 64) * 8]);
            const short* gb = W2p + (size_t)(nb * 128 + row) * 256 + k0 + colg * 8;
            async_copy16(gb, &Bs[(r * 256 + wave * 64) * 8]);
        }
        __syncthreads();
        #pragma unroll
        for (int kc = 0; kc < 2; ++kc) {
            bf16x8 af[4], bfr[4];
            #pragma unroll
            for (int it = 0; it < 4; ++it) {
                int rowa = i0w + it * 16 + ln15;
                int c8a = (kc * 4 + quad) ^ (rowa & 7);
                af[it] = *(const bf16x8*)&As[rowa * 64 + c8a * 8];
                int rowb = n0w + it * 16 + ln15;
                int c8b = (kc * 4 + quad) ^ (rowb & 7);
                bfr[it] = *(const bf16x8*)&Bs[rowb * 64 + c8b * 8];
            }
            #pragma unroll
            for (int it = 0; it < 4; ++it)
                #pragma unroll
                for (int nt = 0; nt < 4; ++nt)
                    acc[it][nt] = __builtin_amdgcn_mfma_f32_16x16x32_bf16(
                        bfr[nt], af[it], acc[it][nt], 0, 0, 0);
        }
        __syncthreads();
    }
    #pragma unroll
    for (int it = 0; it < 4; ++it) {
        size_t pos = posBase + i0w + it * 16 + ln15;
        #pragma unroll
        for (int nt = 0; nt < 4; ++nt) {
            int ncol0 = nb * 128 + n0w + nt * 16 + quad * 4;
            const float4 fbv = *(const float4*)&fb[ncol0];
            float4 o;
            o.x = acc[it][nt][0] + fbv.x;
            o.y = acc[it][nt][1] + fbv.y;
            o.z = acc[it][nt][2] + fbv.z;
            o.w = acc[it][nt][3] + fbv.w;
            *(float4*)&out[pos * 256 + ncol0] = o;
        }
    }
}

extern "C" void kernel_launch(void* const* d_in, const int* in_sizes, int n_in,
                              void* d_out, int out_size, void* d_ws, size_t ws_size,
                              hipStream_t stream) {
    const float* x1d     = (const float*)d_in[0];
    const float* x2d     = (const float*)d_in[1];
    const float* norm_w  = (const float*)d_in[2];
    const float* norm_b  = (const float*)d_in[3];
    const float* qkv_w   = (const float*)d_in[4];
    const float* x2d_w   = (const float*)d_in[5];
    const float* gate_w  = (const float*)d_in[6];
    const float* gate_b  = (const float*)d_in[7];
    const float* final_w = (const float*)d_in[8];
    const float* final_b = (const float*)d_in[9];
    float* out = (float*)d_out;
    char* w = (char*)d_ws;

    short* Ahi   = (short*)(w + OFF_AHI);
    short* attnB = (short*)(w + OFF_ATTN);
    float* biasT = (float*)(w + OFF_BIAST);
    short* Whi   = (short*)(w + OFF_WHI);
    short* W2p   = (short*)(w + OFF_W2P);
    float* gbp   = (float*)(w + OFF_GBP);

    k_prep<<<10497, 256, 0, stream>>>(x1d, norm_w, norm_b, qkv_w, gate_w, gate_b,
                                      final_w, x2d, x2d_w, Ahi, Whi, W2p, gbp, biasT);
    k_fused<<<1024, 512, 0, stream>>>(Ahi, Whi, gbp, biasT, attnB);
    k_gemm2m<<<dim3(256, 2), 256, 0, stream>>>(attnB, W2p, final_b, out);
}

// Round 14
// 205.193 us; speedup vs baseline: 1.8264x; 1.8264x over previous
//
#include <hip/hip_runtime.h>
#include <math.h>

typedef short bf16x8 __attribute__((ext_vector_type(8)));
typedef float f32x4  __attribute__((ext_vector_type(4)));

#define NPOS 32768
#define LOG2E 1.4426950408889634f

// ---- workspace byte offsets ----
#define OFF_GG    0u            // short [32768][256]   16777216  (gate relay, old Chi region)
#define OFF_AHI   100663296u    // short [32768][256]   16777216
#define OFF_ATTN  134217728u    // short [32768][256]   16777216
#define OFF_BIAST 150994944u    // float [8][256][256]   2097152  (layout [h][j][i], LOG2E-prescaled)
#define OFF_WHI   153354240u    // short [1024][256]      524288
#define OFF_W2P   154402816u    // short [256][256]       131072
#define OFF_GBP   154533888u    // float [256]              1024

__device__ __forceinline__ short f2bf(float x) {
    unsigned int u = __float_as_uint(x);
    unsigned int r = (u + 0x7FFFu + ((u >> 16) & 1u)) >> 16;
    return (short)r;
}
__device__ __forceinline__ float bf2f(short s) {
    return __uint_as_float(((unsigned int)(unsigned short)s) << 16);
}
__device__ __forceinline__ void async_copy16(const void* g, void* l) {
    __builtin_amdgcn_global_load_lds(
        (const __attribute__((address_space(1))) unsigned int*)g,
        (__attribute__((address_space(3))) unsigned int*)l, 16, 0, 0);
}

// ---------------- kernel 1: fused prep (ln_cast | castw | bias2) ----------------
#define PREP_LN   8192
#define PREP_CW   9473
__global__ __launch_bounds__(256) void k_prep(
    const float* __restrict__ x, const float* __restrict__ nw, const float* __restrict__ nb,
    const float* __restrict__ qkvw, const float* __restrict__ gatew,
    const float* __restrict__ gateb, const float* __restrict__ finalw,
    const float* __restrict__ x2d, const float* __restrict__ x2dw,
    short* __restrict__ Ahi, short* __restrict__ Whi, short* __restrict__ W2p,
    float* __restrict__ gbp, float* __restrict__ biasT) {
    __shared__ float xs[64][132];
    __shared__ float ws[8][132];
    const int bid = blockIdx.x;
    const int t = threadIdx.x;

    if (bid < PREP_LN) {                       // ---- layernorm + cast ----
        int wid = (bid * 256 + t) >> 6;
        int lane = t & 63;
        const float4 v = ((const float4*)(x + (size_t)wid * 256))[lane];
        float s  = v.x + v.y + v.z + v.w;
        float ss = v.x*v.x + v.y*v.y + v.z*v.z + v.w*v.w;
        #pragma unroll
        for (int o = 32; o; o >>= 1) {
            s  += __shfl_xor(s,  o, 64);
            ss += __shfl_xor(ss, o, 64);
        }
        float mu  = s * (1.0f / 256);
        float var = ss * (1.0f / 256) - mu * mu;
        float rs  = rsqrtf(var + 1e-5f);
        const float4 wv = ((const float4*)nw)[lane];
        const float4 bv = ((const float4*)nb)[lane];
        float y[4] = {(v.x - mu) * rs * wv.x + bv.x, (v.y - mu) * rs * wv.y + bv.y,
                      (v.z - mu) * rs * wv.z + bv.z, (v.w - mu) * rs * wv.w + bv.w};
        short h4[4];
        #pragma unroll
        for (int i = 0; i < 4; ++i) h4[i] = f2bf(y[i]);
        *(short4*)(Ahi + (size_t)wid * 256 + lane * 4) = *(short4*)h4;
    } else if (bid < PREP_CW) {                // ---- weight permute + cast ----
        int r = bid - PREP_LN;
        if (r < 1024) {
            int which = r >> 8, h = (r >> 5) & 7, c = r & 31;
            const float* src = (which < 3) ? qkvw + (size_t)(c * 24 + which * 8 + h) * 256
                                           : gatew + (size_t)(c * 8 + h) * 256;
            Whi[(size_t)r * 256 + t] = f2bf(src[t]);
        } else if (r < 1280) {
            int o = r - 1024;
            int h = t >> 5, c = t & 31;
            W2p[(size_t)o * 256 + t] = f2bf(finalw[(size_t)o * 256 + c * 8 + h]);
        } else {
            int h = t >> 5, c = t & 31;
            gbp[t] = gateb[c * 8 + h];
        }
    } else {                                   // ---- pair bias (layout [h][j][i]) ----
        const int wid0 = (bid - PREP_CW) * 64;
        #pragma unroll
        for (int r = 0; r < 8; ++r) {
            int g = r * 256 + t;
            int row = g >> 5, c4 = g & 31;
            float4 v = *(const float4*)(x2d + (size_t)(wid0 + row) * 128 + c4 * 4);
            *(float4*)&xs[row][c4 * 4] = v;
        }
        {
            int h = t >> 5, c4 = t & 31;
            *(float4*)&ws[h][c4 * 4] = *(const float4*)(x2dw + h * 128 + c4 * 4);
        }
        __syncthreads();
        const float f = 0.17677669529663687f * LOG2E;   // prescaled for exp2 softmax
        const int i = wid0 >> 8;
        #pragma unroll
        for (int kk = 0; kk < 2; ++kk) {
            int o = t + kk * 256;
            int row = o >> 3, h = o & 7;
            float acc = 0.f;
            #pragma unroll
            for (int c4 = 0; c4 < 32; ++c4) {
                float4 xv = *(const float4*)&xs[row][c4 * 4];
                float4 wv = *(const float4*)&ws[h][c4 * 4];
                acc += xv.x * wv.x + xv.y * wv.y + xv.z * wv.z + xv.w * wv.w;
            }
            int j = (wid0 & 255) + row;
            biasT[(((h * 256 + j)) << 8) + i] = acc * f;
        }
    }
}

// ---------------- kernel 2: FUSED qkv-gemm + attention per (m,h) ----------------
// Phase 1: C[256x128] = A[m-panel] @ W[h-cols] (bit-identical MFMA order).
// Q relays through per-wave Pl scratch; gate streams to global Gg (old Chi
// region) and is read back in the final epilogue (r5 attn3 pattern).
// LDS arena = max(phase1 48K, phase2 Khi+VT+Pl 43.5K) = 49152 B -> 3 blocks/CU.
// NO min-waves launch bound: r13's (512,6) forced VGPR 40 -> 704MB scratch spill.
__global__ __launch_bounds__(512) void k_fused(
    const short* __restrict__ Ahi, const short* __restrict__ Whi,
    const float* __restrict__ gbp, const float* __restrict__ biasT,
    short* __restrict__ Gg, short* __restrict__ attnB) {
    __shared__ __align__(16) short smem[24576];   // 49152 B
    short* As  = smem;              // [256][64]  (phase 1, 16384 shorts)
    short* Ws  = smem + 16384;      // [128][64]  (phase 1, 8192 shorts)
    short* Khi = smem;              // [256][32] swizzled (phase 2)
    short* VT  = smem + 8192;       // [32][264]  (8448 shorts)
    short* Pl  = smem + 16640;      // [8][16][40] per-wave scratch (5120 shorts)

    const int mh = blockIdx.x;
    const int h = mh >> 7, m = mh & 127;       // h-major: A-panel sharers on same XCD
    const int t = threadIdx.x;
    const int wave = t >> 6, lane = t & 63, ln15 = lane & 15, quad = lane >> 4;
    const int i0 = wave * 32;

    f32x4 acc[2][8];
    #pragma unroll
    for (int a = 0; a < 2; ++a)
        #pragma unroll
        for (int b = 0; b < 8; ++b) acc[a][b] = (f32x4){0.f, 0.f, 0.f, 0.f};

    // ---- phase 1: GEMM ----
    for (int k0 = 0; k0 < 256; k0 += 64) {
        #pragma unroll
        for (int r = 0; r < 4; ++r) {          // A: 256 rows x 64
            int g = r * 512 + t;
            int row = g >> 3, cs = g & 7;
            int colg = cs ^ (row & 7);
            async_copy16(Ahi + (size_t)(m * 256 + row) * 256 + k0 + colg * 8, &As[g * 8]);
        }
        #pragma unroll
        for (int r = 0; r < 2; ++r) {          // W: 128 rows x 64 (q,k,v,g for head h)
            int g = r * 512 + t;
            int row = g >> 3, cs = g & 7;
            int colg = cs ^ (row & 7);
            int nrow = (row >> 5) * 256 + h * 32 + (row & 31);
            async_copy16(Whi + (size_t)nrow * 256 + k0 + colg * 8, &Ws[g * 8]);
        }
        __syncthreads();
        #pragma unroll
        for (int kc = 0; kc < 2; ++kc) {
            bf16x8 af[2], bfr[8];
            #pragma unroll
            for (int it = 0; it < 2; ++it) {
                int rowa = i0 + it * 16 + ln15;
                int c8a = (kc * 4 + quad) ^ (rowa & 7);
                af[it] = *(const bf16x8*)&As[rowa * 64 + c8a * 8];
            }
            #pragma unroll
            for (int nt = 0; nt < 8; ++nt) {
                int rowb = nt * 16 + ln15;
                int c8b = (kc * 4 + quad) ^ (rowb & 7);
                bfr[nt] = *(const bf16x8*)&Ws[rowb * 64 + c8b * 8];
            }
            #pragma unroll
            for (int it = 0; it < 2; ++it)
                #pragma unroll
                for (int nt = 0; nt < 8; ++nt)
                    acc[it][nt] = __builtin_amdgcn_mfma_f32_16x16x32_bf16(
                        bfr[nt], af[it], acc[it][nt], 0, 0, 0);
        }
        __syncthreads();                        // also guards the overlay below
    }

    // ---- epilogue: K->Khi, V->VT, Q->per-wave Pl relay, gate->global Gg ----
    bf16x8 qhi[2];
    short* plrow = &Pl[(wave * 16 + ln15) * 40];
    #pragma unroll
    for (int it = 0; it < 2; ++it) {
        int j = i0 + it * 16 + ln15;
        int sw = j & 3;
        #pragma unroll
        for (int nt = 0; nt < 8; ++nt) {
            int which = nt >> 1;
            int cloc0 = (nt & 1) * 16 + quad * 4;
            float v0 = acc[it][nt][0], v1 = acc[it][nt][1];
            float v2 = acc[it][nt][2], v3 = acc[it][nt][3];
            if (which == 3) {
                const float4 gb = *(const float4*)&gbp[h * 32 + cloc0];
                v0 = 1.0f / (1.0f + __expf(-(v0 + gb.x)));
                v1 = 1.0f / (1.0f + __expf(-(v1 + gb.y)));
                v2 = 1.0f / (1.0f + __expf(-(v2 + gb.z)));
                v3 = 1.0f / (1.0f + __expf(-(v3 + gb.w)));
            }
            short s0 = f2bf(v0), s1 = f2bf(v1), s2 = f2bf(v2), s3 = f2bf(v3);
            if (which == 2) {                   // V transposed, scalar stores
                VT[(cloc0 + 0) * 264 + j] = s0;
                VT[(cloc0 + 1) * 264 + j] = s1;
                VT[(cloc0 + 2) * 264 + j] = s2;
                VT[(cloc0 + 3) * 264 + j] = s3;
            } else {
                unsigned w0 = (unsigned)(unsigned short)s0 | ((unsigned)(unsigned short)s1 << 16);
                unsigned w1 = (unsigned)(unsigned short)s2 | ((unsigned)(unsigned short)s3 << 16);
                if (which == 0) {               // Q -> per-wave Pl relay
                    *(uint2*)&plrow[cloc0] = make_uint2(w0, w1);
                } else if (which == 1) {        // K -> Khi (swizzled, cross-wave)
                    int cg = cloc0 >> 3, off = cloc0 & 7;
                    *(uint2*)&Khi[j * 32 + (cg ^ sw) * 8 + off] = make_uint2(w0, w1);
                } else {                        // gate -> global (coalesced uint2)
                    *(uint2*)&Gg[(size_t)(m * 256 + j) * 256 + h * 32 + cloc0] =
                        make_uint2(w0, w1);
                }
            }
        }
        qhi[it] = *(const bf16x8*)&plrow[quad * 8];   // wave-local, in-order LDS
    }
    __syncthreads();

    // ---- phase 2: attention (exp2-domain softmax) ----
    float lacc[2] = {0.f, 0.f};
    f32x4 Oacc[2][2];
    #pragma unroll
    for (int a = 0; a < 2; ++a) {
        Oacc[a][0] = (f32x4){0.f, 0.f, 0.f, 0.f};
        Oacc[a][1] = (f32x4){0.f, 0.f, 0.f, 0.f};
    }
    const float* bp = biasT + (size_t)h * 65536;   // [j][i], LOG2E-prescaled

    for (int j0 = 0; j0 < 256; j0 += 32) {
        bf16x8 kfh[2], vf[2];
        #pragma unroll
        for (int jt = 0; jt < 2; ++jt) {
            int j = j0 + jt * 16 + ln15;
            int cs = quad ^ (j & 3);
            kfh[jt] = *(const bf16x8*)&Khi[j * 32 + cs * 8];
        }
        #pragma unroll
        for (int ct = 0; ct < 2; ++ct) {
            int c = ct * 16 + ln15;
            vf[ct] = *(const bf16x8*)&VT[c * 264 + j0 + quad * 8];
        }
        #pragma unroll
        for (int it = 0; it < 2; ++it) {
            int i = i0 + it * 16 + ln15;
            float b0[4], b1[4];
            #pragma unroll
            for (int r = 0; r < 4; ++r) {
                b0[r] = bp[(j0 + quad * 4 + r) * 256 + i];
                b1[r] = bp[(j0 + 16 + quad * 4 + r) * 256 + i];
            }
            f32x4 s0 = (f32x4){0.f, 0.f, 0.f, 0.f};
            f32x4 s1 = (f32x4){0.f, 0.f, 0.f, 0.f};
            s0 = __builtin_amdgcn_mfma_f32_16x16x32_bf16(kfh[0], qhi[it], s0, 0, 0, 0);
            s1 = __builtin_amdgcn_mfma_f32_16x16x32_bf16(kfh[1], qhi[it], s1, 0, 0, 0);
            // unnormalized softmax in exp2 domain: p = 2^(s*log2e + b_pre)
            float p[8], ps = 0.f;
            #pragma unroll
            for (int r = 0; r < 4; ++r) {
                p[r] = __builtin_amdgcn_exp2f(fmaf(s0[r], LOG2E, b0[r]));
                ps += p[r];
            }
            #pragma unroll
            for (int r = 0; r < 4; ++r) {
                p[4 + r] = __builtin_amdgcn_exp2f(fmaf(s1[r], LOG2E, b1[r]));
                ps += p[4 + r];
            }
            lacc[it] += ps;
            unsigned long long pw0 =
                  (unsigned long long)(unsigned short)f2bf(p[0])
                | ((unsigned long long)(unsigned short)f2bf(p[1]) << 16)
                | ((unsigned long long)(unsigned short)f2bf(p[2]) << 32)
                | ((unsigned long long)(unsigned short)f2bf(p[3]) << 48);
            unsigned long long pw1 =
                  (unsigned long long)(unsigned short)f2bf(p[4])
                | ((unsigned long long)(unsigned short)f2bf(p[5]) << 16)
                | ((unsigned long long)(unsigned short)f2bf(p[6]) << 32)
                | ((unsigned long long)(unsigned short)f2bf(p[7]) << 48);
            *(unsigned long long*)&plrow[quad * 4]      = pw0;
            *(unsigned long long*)&plrow[16 + quad * 4] = pw1;
            bf16x8 pf = *(const bf16x8*)&plrow[quad * 8];
            Oacc[it][0] = __builtin_amdgcn_mfma_f32_16x16x32_bf16(pf, vf[0], Oacc[it][0], 0, 0, 0);
            Oacc[it][1] = __builtin_amdgcn_mfma_f32_16x16x32_bf16(pf, vf[1], Oacc[it][1], 0, 0, 0);
        }
    }
    #pragma unroll
    for (int it = 0; it < 2; ++it) {
        float l = lacc[it];
        l += __shfl_xor(l, 16, 64);
        l += __shfl_xor(l, 32, 64);
        float inv = 1.0f / l;
        float invr[4];
        #pragma unroll
        for (int r = 0; r < 4; ++r) invr[r] = __shfl(inv, quad * 4 + r, 16);
        #pragma unroll
        for (int ct = 0; ct < 2; ++ct) {
            int c = ct * 16 + ln15;
            #pragma unroll
            for (int r = 0; r < 4; ++r) {
                int i = i0 + it * 16 + quad * 4 + r;
                float g = bf2f(Gg[(size_t)(m * 256 + i) * 256 + h * 32 + c]);
                float val = Oacc[it][ct][r] * invr[r] * g;
                attnB[(size_t)(m * 256 + i) * 256 + h * 32 + c] = f2bf(val);
            }
        }
    }
}

// ---------------- kernel 3: MFMA GEMM2, single-buffer, transposed-frag epilogue ----------------
__global__ __launch_bounds__(256) void k_gemm2m(
    const short* __restrict__ A, const short* __restrict__ W2p,
    const float* __restrict__ fb, float* __restrict__ out) {
    __shared__ short As[128 * 64];
    __shared__ short Bs[128 * 64];
    const int t = threadIdx.x;
    const int wave = t >> 6, lane = t & 63, ln15 = lane & 15, quad = lane >> 4;
    const int posBase = blockIdx.x * 128;
    const int nb = blockIdx.y;
    const int i0w = (wave & 1) * 64, n0w = (wave >> 1) * 64;

    f32x4 acc[4][4];
    #pragma unroll
    for (int a = 0; a < 4; ++a)
        #pragma unroll
        for (int b = 0; b < 4; ++b) acc[a][b] = (f32x4){0.f, 0.f, 0.f, 0.f};

    for (int k0 = 0; k0 < 256; k0 += 64) {
        #pragma unroll
        for (int r = 0; r < 4; ++r) {
            int g = r * 256 + t;
            int row = g >> 3, cs = g & 7;
            int colg = cs ^ (row & 7);
            const short* ga = A + (size_t)(posBase + row) * 256 + k0 + colg * 8;
            async_copy16(ga, &As[(r * 256 + wave * 64) * 8]);
            const short* gb = W2p + (size_t)(nb * 128 + row) * 256 + k0 + colg * 8;
            async_copy16(gb, &Bs[(r * 256 + wave * 64) * 8]);
        }
        __syncthreads();
        #pragma unroll
        for (int kc = 0; kc < 2; ++kc) {
            bf16x8 af[4], bfr[4];
            #pragma unroll
            for (int it = 0; it < 4; ++it) {
                int rowa = i0w + it * 16 + ln15;
                int c8a = (kc * 4 + quad) ^ (rowa & 7);
                af[it] = *(const bf16x8*)&As[rowa * 64 + c8a * 8];
                int rowb = n0w + it * 16 + ln15;
                int c8b = (kc * 4 + quad) ^ (rowb & 7);
                bfr[it] = *(const bf16x8*)&Bs[rowb * 64 + c8b * 8];
            }
            #pragma unroll
            for (int it = 0; it < 4; ++it)
                #pragma unroll
                for (int nt = 0; nt < 4; ++nt)
                    acc[it][nt] = __builtin_amdgcn_mfma_f32_16x16x32_bf16(
                        bfr[nt], af[it], acc[it][nt], 0, 0, 0);
        }
        __syncthreads();
    }
    #pragma unroll
    for (int it = 0; it < 4; ++it) {
        size_t pos = posBase + i0w + it * 16 + ln15;
        #pragma unroll
        for (int nt = 0; nt < 4; ++nt) {
            int ncol0 = nb * 128 + n0w + nt * 16 + quad * 4;
            const float4 fbv = *(const float4*)&fb[ncol0];
            float4 o;
            o.x = acc[it][nt][0] + fbv.x;
            o.y = acc[it][nt][1] + fbv.y;
            o.z = acc[it][nt][2] + fbv.z;
            o.w = acc[it][nt][3] + fbv.w;
            *(float4*)&out[pos * 256 + ncol0] = o;
        }
    }
}

extern "C" void kernel_launch(void* const* d_in, const int* in_sizes, int n_in,
                              void* d_out, int out_size, void* d_ws, size_t ws_size,
                              hipStream_t stream) {
    const float* x1d     = (const float*)d_in[0];
    const float* x2d     = (const float*)d_in[1];
    const float* norm_w  = (const float*)d_in[2];
    const float* norm_b  = (const float*)d_in[3];
    const float* qkv_w   = (const float*)d_in[4];
    const float* x2d_w   = (const float*)d_in[5];
    const float* gate_w  = (const float*)d_in[6];
    const float* gate_b  = (const float*)d_in[7];
    const float* final_w = (const float*)d_in[8];
    const float* final_b = (const float*)d_in[9];
    float* out = (float*)d_out;
    char* w = (char*)d_ws;

    short* Gg    = (short*)(w + OFF_GG);
    short* Ahi   = (short*)(w + OFF_AHI);
    short* attnB = (short*)(w + OFF_ATTN);
    float* biasT = (float*)(w + OFF_BIAST);
    short* Whi   = (short*)(w + OFF_WHI);
    short* W2p   = (short*)(w + OFF_W2P);
    float* gbp   = (float*)(w + OFF_GBP);

    k_prep<<<10497, 256, 0, stream>>>(x1d, norm_w, norm_b, qkv_w, gate_w, gate_b,
                                      final_w, x2d, x2d_w, Ahi, Whi, W2p, gbp, biasT);
    k_fused<<<1024, 512, 0, stream>>>(Ahi, Whi, gbp, biasT, Gg, attnB);
    k_gemm2m<<<dim3(256, 2), 256, 0, stream>>>(attnB, W2p, final_b, out);
}

// Round 15
// 189.789 us; speedup vs baseline: 1.9746x; 1.0812x over previous
//
#include <hip/hip_runtime.h>
#include <math.h>

typedef short bf16x8 __attribute__((ext_vector_type(8)));
typedef float f32x4  __attribute__((ext_vector_type(4)));

#define NPOS 32768
#define LOG2E 1.4426950408889634f

// ---- workspace byte offsets ----
#define OFF_AHI   100663296u    // short [32768][256]   16777216
#define OFF_ATTN  134217728u    // short [32768][256]   16777216
#define OFF_BIAST 150994944u    // float [8][256][256]   2097152  (layout [h][j][i], LOG2E-prescaled)
#define OFF_WHI   153354240u    // short [1024][256]      524288
#define OFF_W2P   154402816u    // short [256][256]       131072
#define OFF_GBP   154533888u    // float [256]              1024

__device__ __forceinline__ short f2bf(float x) {
    unsigned int u = __float_as_uint(x);
    unsigned int r = (u + 0x7FFFu + ((u >> 16) & 1u)) >> 16;
    return (short)r;
}
__device__ __forceinline__ float bf2f(short s) {
    return __uint_as_float(((unsigned int)(unsigned short)s) << 16);
}
__device__ __forceinline__ void async_copy16(const void* g, void* l) {
    __builtin_amdgcn_global_load_lds(
        (const __attribute__((address_space(1))) unsigned int*)g,
        (__attribute__((address_space(3))) unsigned int*)l, 16, 0, 0);
}

// ---------------- kernel 1: fused prep (ln_cast | castw | bias2) ----------------
#define PREP_LN   8192
#define PREP_CW   9473
__global__ __launch_bounds__(256) void k_prep(
    const float* __restrict__ x, const float* __restrict__ nw, const float* __restrict__ nb,
    const float* __restrict__ qkvw, const float* __restrict__ gatew,
    const float* __restrict__ gateb, const float* __restrict__ finalw,
    const float* __restrict__ x2d, const float* __restrict__ x2dw,
    short* __restrict__ Ahi, short* __restrict__ Whi, short* __restrict__ W2p,
    float* __restrict__ gbp, float* __restrict__ biasT) {
    __shared__ float xs[64][132];
    __shared__ float ws[8][132];
    const int bid = blockIdx.x;
    const int t = threadIdx.x;

    if (bid < PREP_LN) {                       // ---- layernorm + cast ----
        int wid = (bid * 256 + t) >> 6;
        int lane = t & 63;
        const float4 v = ((const float4*)(x + (size_t)wid * 256))[lane];
        float s  = v.x + v.y + v.z + v.w;
        float ss = v.x*v.x + v.y*v.y + v.z*v.z + v.w*v.w;
        #pragma unroll
        for (int o = 32; o; o >>= 1) {
            s  += __shfl_xor(s,  o, 64);
            ss += __shfl_xor(ss, o, 64);
        }
        float mu  = s * (1.0f / 256);
        float var = ss * (1.0f / 256) - mu * mu;
        float rs  = rsqrtf(var + 1e-5f);
        const float4 wv = ((const float4*)nw)[lane];
        const float4 bv = ((const float4*)nb)[lane];
        float y[4] = {(v.x - mu) * rs * wv.x + bv.x, (v.y - mu) * rs * wv.y + bv.y,
                      (v.z - mu) * rs * wv.z + bv.z, (v.w - mu) * rs * wv.w + bv.w};
        short h4[4];
        #pragma unroll
        for (int i = 0; i < 4; ++i) h4[i] = f2bf(y[i]);
        *(short4*)(Ahi + (size_t)wid * 256 + lane * 4) = *(short4*)h4;
    } else if (bid < PREP_CW) {                // ---- weight permute + cast ----
        int r = bid - PREP_LN;
        if (r < 1024) {
            int which = r >> 8, h = (r >> 5) & 7, c = r & 31;
            const float* src = (which < 3) ? qkvw + (size_t)(c * 24 + which * 8 + h) * 256
                                           : gatew + (size_t)(c * 8 + h) * 256;
            Whi[(size_t)r * 256 + t] = f2bf(src[t]);
        } else if (r < 1280) {
            int o = r - 1024;
            int h = t >> 5, c = t & 31;
            W2p[(size_t)o * 256 + t] = f2bf(finalw[(size_t)o * 256 + c * 8 + h]);
        } else {
            int h = t >> 5, c = t & 31;
            gbp[t] = gateb[c * 8 + h];
        }
    } else {                                   // ---- pair bias (layout [h][j][i]) ----
        const int wid0 = (bid - PREP_CW) * 64;
        #pragma unroll
        for (int r = 0; r < 8; ++r) {
            int g = r * 256 + t;
            int row = g >> 5, c4 = g & 31;
            float4 v = *(const float4*)(x2d + (size_t)(wid0 + row) * 128 + c4 * 4);
            *(float4*)&xs[row][c4 * 4] = v;
        }
        {
            int h = t >> 5, c4 = t & 31;
            *(float4*)&ws[h][c4 * 4] = *(const float4*)(x2dw + h * 128 + c4 * 4);
        }
        __syncthreads();
        const float f = 0.17677669529663687f * LOG2E;   // prescaled for exp2 softmax
        const int i = wid0 >> 8;
        #pragma unroll
        for (int kk = 0; kk < 2; ++kk) {
            int o = t + kk * 256;
            int row = o >> 3, h = o & 7;
            float acc = 0.f;
            #pragma unroll
            for (int c4 = 0; c4 < 32; ++c4) {
                float4 xv = *(const float4*)&xs[row][c4 * 4];
                float4 wv = *(const float4*)&ws[h][c4 * 4];
                acc += xv.x * wv.x + xv.y * wv.y + xv.z * wv.z + xv.w * wv.w;
            }
            int j = (wid0 & 255) + row;
            biasT[(((h * 256 + j)) << 8) + i] = acc * f;
        }
    }
}

// ---------------- kernel 2: FUSED qkv-gemm + attention per (m,h) ----------------
// r12 structure (best known: 51.7us) + T5 setprio around phase-2 MFMA clusters.
// Phase 1: C[256x128] = A[m-panel] @ W[h-cols] (bit-identical MFMA order),
// epilogue relays bf16 Q/K/V/G into LDS. Phase 2: attn3 body, exp2 softmax.
// LDS arena: phase1 {As 32K | Ws 16K} overlaid by phase2 {Khi|VT|Qs|Gs|Pl} = 76288 B.
__global__ __launch_bounds__(512, 4) void k_fused(
    const short* __restrict__ Ahi, const short* __restrict__ Whi,
    const float* __restrict__ gbp, const float* __restrict__ biasT,
    short* __restrict__ attnB) {
    __shared__ __align__(16) short smem[38144];
    short* As  = smem;              // [256][64]  (phase 1)
    short* Ws  = smem + 16384;      // [128][64]  (phase 1)
    short* Khi = smem;              // [256][32] swizzled (phase 2)
    short* VT  = smem + 8192;       // [32][264]
    short* Qs  = smem + 16640;      // [256][32] swizzled
    short* Gs  = smem + 24832;      // [256][32]
    short* Pl  = smem + 33024;      // [8][16][40]

    const int mh = blockIdx.x;
    const int h = mh >> 7, m = mh & 127;       // h-major: A-panel sharers on same XCD
    const int t = threadIdx.x;
    const int wave = t >> 6, lane = t & 63, ln15 = lane & 15, quad = lane >> 4;
    const int i0 = wave * 32;

    f32x4 acc[2][8];
    #pragma unroll
    for (int a = 0; a < 2; ++a)
        #pragma unroll
        for (int b = 0; b < 8; ++b) acc[a][b] = (f32x4){0.f, 0.f, 0.f, 0.f};

    // ---- phase 1: GEMM ----
    for (int k0 = 0; k0 < 256; k0 += 64) {
        #pragma unroll
        for (int r = 0; r < 4; ++r) {          // A: 256 rows x 64
            int g = r * 512 + t;
            int row = g >> 3, cs = g & 7;
            int colg = cs ^ (row & 7);
            async_copy16(Ahi + (size_t)(m * 256 + row) * 256 + k0 + colg * 8, &As[g * 8]);
        }
        #pragma unroll
        for (int r = 0; r < 2; ++r) {          // W: 128 rows x 64 (q,k,v,g for head h)
            int g = r * 512 + t;
            int row = g >> 3, cs = g & 7;
            int colg = cs ^ (row & 7);
            int nrow = (row >> 5) * 256 + h * 32 + (row & 31);
            async_copy16(Whi + (size_t)nrow * 256 + k0 + colg * 8, &Ws[g * 8]);
        }
        __syncthreads();
        #pragma unroll
        for (int kc = 0; kc < 2; ++kc) {
            bf16x8 af[2], bfr[8];
            #pragma unroll
            for (int it = 0; it < 2; ++it) {
                int rowa = i0 + it * 16 + ln15;
                int c8a = (kc * 4 + quad) ^ (rowa & 7);
                af[it] = *(const bf16x8*)&As[rowa * 64 + c8a * 8];
            }
            #pragma unroll
            for (int nt = 0; nt < 8; ++nt) {
                int rowb = nt * 16 + ln15;
                int c8b = (kc * 4 + quad) ^ (rowb & 7);
                bfr[nt] = *(const bf16x8*)&Ws[rowb * 64 + c8b * 8];
            }
            #pragma unroll
            for (int it = 0; it < 2; ++it)
                #pragma unroll
                for (int nt = 0; nt < 8; ++nt)
                    acc[it][nt] = __builtin_amdgcn_mfma_f32_16x16x32_bf16(
                        bfr[nt], af[it], acc[it][nt], 0, 0, 0);
        }
        __syncthreads();                        // also guards the overlay below
    }

    // ---- epilogue: C -> LDS bf16 tiles (lane holds row j, 4 consecutive cols) ----
    #pragma unroll
    for (int it = 0; it < 2; ++it) {
        int j = i0 + it * 16 + ln15;
        int sw = j & 3;
        #pragma unroll
        for (int nt = 0; nt < 8; ++nt) {
            int which = nt >> 1;
            int cloc0 = (nt & 1) * 16 + quad * 4;
            float v0 = acc[it][nt][0], v1 = acc[it][nt][1];
            float v2 = acc[it][nt][2], v3 = acc[it][nt][3];
            if (which == 3) {
                const float4 gb = *(const float4*)&gbp[h * 32 + cloc0];
                v0 = 1.0f / (1.0f + __expf(-(v0 + gb.x)));
                v1 = 1.0f / (1.0f + __expf(-(v1 + gb.y)));
                v2 = 1.0f / (1.0f + __expf(-(v2 + gb.z)));
                v3 = 1.0f / (1.0f + __expf(-(v3 + gb.w)));
            }
            short s0 = f2bf(v0), s1 = f2bf(v1), s2 = f2bf(v2), s3 = f2bf(v3);
            if (which == 2) {                   // V transposed, scalar stores
                VT[(cloc0 + 0) * 264 + j] = s0;
                VT[(cloc0 + 1) * 264 + j] = s1;
                VT[(cloc0 + 2) * 264 + j] = s2;
                VT[(cloc0 + 3) * 264 + j] = s3;
            } else {
                unsigned w0 = (unsigned)(unsigned short)s0 | ((unsigned)(unsigned short)s1 << 16);
                unsigned w1 = (unsigned)(unsigned short)s2 | ((unsigned)(unsigned short)s3 << 16);
                int cg = cloc0 >> 3, off = cloc0 & 7;
                short* dst = (which == 0) ? &Qs[j * 32 + (cg ^ sw) * 8 + off]
                           : (which == 1) ? &Khi[j * 32 + (cg ^ sw) * 8 + off]
                                          : &Gs[j * 32 + cloc0];
                *(uint2*)dst = make_uint2(w0, w1);
            }
        }
    }
    __syncthreads();

    // ---- phase 2: attention (LDS-sourced Q/K/G, exp2-domain softmax) ----
    bf16x8 qhi[2];
    #pragma unroll
    for (int it = 0; it < 2; ++it) {
        int i = i0 + it * 16 + ln15;
        qhi[it] = *(const bf16x8*)&Qs[i * 32 + ((quad ^ (i & 3))) * 8];
    }
    float lacc[2] = {0.f, 0.f};
    f32x4 Oacc[2][2];
    #pragma unroll
    for (int a = 0; a < 2; ++a) {
        Oacc[a][0] = (f32x4){0.f, 0.f, 0.f, 0.f};
        Oacc[a][1] = (f32x4){0.f, 0.f, 0.f, 0.f};
    }
    const float* bp = biasT + (size_t)h * 65536;   // [j][i], LOG2E-prescaled

    for (int j0 = 0; j0 < 256; j0 += 32) {
        bf16x8 kfh[2], vf[2];
        #pragma unroll
        for (int jt = 0; jt < 2; ++jt) {
            int j = j0 + jt * 16 + ln15;
            int cs = quad ^ (j & 3);
            kfh[jt] = *(const bf16x8*)&Khi[j * 32 + cs * 8];
        }
        #pragma unroll
        for (int ct = 0; ct < 2; ++ct) {
            int c = ct * 16 + ln15;
            vf[ct] = *(const bf16x8*)&VT[c * 264 + j0 + quad * 8];
        }
        #pragma unroll
        for (int it = 0; it < 2; ++it) {
            int i = i0 + it * 16 + ln15;
            float b0[4], b1[4];
            #pragma unroll
            for (int r = 0; r < 4; ++r) {
                b0[r] = bp[(j0 + quad * 4 + r) * 256 + i];
                b1[r] = bp[(j0 + 16 + quad * 4 + r) * 256 + i];
            }
            f32x4 s0 = (f32x4){0.f, 0.f, 0.f, 0.f};
            f32x4 s1 = (f32x4){0.f, 0.f, 0.f, 0.f};
            __builtin_amdgcn_s_setprio(1);      // T5: favor MFMA-issuing waves
            s0 = __builtin_amdgcn_mfma_f32_16x16x32_bf16(kfh[0], qhi[it], s0, 0, 0, 0);
            s1 = __builtin_amdgcn_mfma_f32_16x16x32_bf16(kfh[1], qhi[it], s1, 0, 0, 0);
            __builtin_amdgcn_s_setprio(0);
            // unnormalized softmax in exp2 domain: p = 2^(s*log2e + b_pre)
            float p[8], ps = 0.f;
            #pragma unroll
            for (int r = 0; r < 4; ++r) {
                p[r] = __builtin_amdgcn_exp2f(fmaf(s0[r], LOG2E, b0[r]));
                ps += p[r];
            }
            #pragma unroll
            for (int r = 0; r < 4; ++r) {
                p[4 + r] = __builtin_amdgcn_exp2f(fmaf(s1[r], LOG2E, b1[r]));
                ps += p[4 + r];
            }
            lacc[it] += ps;
            unsigned long long pw0 =
                  (unsigned long long)(unsigned short)f2bf(p[0])
                | ((unsigned long long)(unsigned short)f2bf(p[1]) << 16)
                | ((unsigned long long)(unsigned short)f2bf(p[2]) << 32)
                | ((unsigned long long)(unsigned short)f2bf(p[3]) << 48);
            unsigned long long pw1 =
                  (unsigned long long)(unsigned short)f2bf(p[4])
                | ((unsigned long long)(unsigned short)f2bf(p[5]) << 16)
                | ((unsigned long long)(unsigned short)f2bf(p[6]) << 32)
                | ((unsigned long long)(unsigned short)f2bf(p[7]) << 48);
            short* plp = &Pl[(wave * 16 + ln15) * 40];
            *(unsigned long long*)&plp[quad * 4]      = pw0;
            *(unsigned long long*)&plp[16 + quad * 4] = pw1;
            bf16x8 pf = *(const bf16x8*)&plp[quad * 8];
            __builtin_amdgcn_s_setprio(1);      // T5: PV cluster
            Oacc[it][0] = __builtin_amdgcn_mfma_f32_16x16x32_bf16(pf, vf[0], Oacc[it][0], 0, 0, 0);
            Oacc[it][1] = __builtin_amdgcn_mfma_f32_16x16x32_bf16(pf, vf[1], Oacc[it][1], 0, 0, 0);
            __builtin_amdgcn_s_setprio(0);
        }
    }
    #pragma unroll
    for (int it = 0; it < 2; ++it) {
        float l = lacc[it];
        l += __shfl_xor(l, 16, 64);
        l += __shfl_xor(l, 32, 64);
        float inv = 1.0f / l;
        float invr[4];
        #pragma unroll
        for (int r = 0; r < 4; ++r) invr[r] = __shfl(inv, quad * 4 + r, 16);
        #pragma unroll
        for (int ct = 0; ct < 2; ++ct) {
            int c = ct * 16 + ln15;
            #pragma unroll
            for (int r = 0; r < 4; ++r) {
                int i = i0 + it * 16 + quad * 4 + r;
                float g = bf2f(Gs[i * 32 + c]);
                float val = Oacc[it][ct][r] * invr[r] * g;
                attnB[(size_t)(m * 256 + i) * 256 + h * 32 + c] = f2bf(val);
            }
        }
    }
}

// ---------------- kernel 3: MFMA GEMM2, single-buffer, transposed-frag epilogue ----------------
__global__ __launch_bounds__(256) void k_gemm2m(
    const short* __restrict__ A, const short* __restrict__ W2p,
    const float* __restrict__ fb, float* __restrict__ out) {
    __shared__ short As[128 * 64];
    __shared__ short Bs[128 * 64];
    const int t = threadIdx.x;
    const int wave = t >> 6, lane = t & 63, ln15 = lane & 15, quad = lane >> 4;
    const int posBase = blockIdx.x * 128;
    const int nb = blockIdx.y;
    const int i0w = (wave & 1) * 64, n0w = (wave >> 1) * 64;

    f32x4 acc[4][4];
    #pragma unroll
    for (int a = 0; a < 4; ++a)
        #pragma unroll
        for (int b = 0; b < 4; ++b) acc[a][b] = (f32x4){0.f, 0.f, 0.f, 0.f};

    for (int k0 = 0; k0 < 256; k0 += 64) {
        #pragma unroll
        for (int r = 0; r < 4; ++r) {
            int g = r * 256 + t;
            int row = g >> 3, cs = g & 7;
            int colg = cs ^ (row & 7);
            const short* ga = A + (size_t)(posBase + row) * 256 + k0 + colg * 8;
            async_copy16(ga, &As[(r * 256 + wave * 64) * 8]);
            const short* gb = W2p + (size_t)(nb * 128 + row) * 256 + k0 + colg * 8;
            async_copy16(gb, &Bs[(r * 256 + wave * 64) * 8]);
        }
        __syncthreads();
        #pragma unroll
        for (int kc = 0; kc < 2; ++kc) {
            bf16x8 af[4], bfr[4];
            #pragma unroll
            for (int it = 0; it < 4; ++it) {
                int rowa = i0w + it * 16 + ln15;
                int c8a = (kc * 4 + quad) ^ (rowa & 7);
                af[it] = *(const bf16x8*)&As[rowa * 64 + c8a * 8];
                int rowb = n0w + it * 16 + ln15;
                int c8b = (kc * 4 + quad) ^ (rowb & 7);
                bfr[it] = *(const bf16x8*)&Bs[rowb * 64 + c8b * 8];
            }
            #pragma unroll
            for (int it = 0; it < 4; ++it)
                #pragma unroll
                for (int nt = 0; nt < 4; ++nt)
                    acc[it][nt] = __builtin_amdgcn_mfma_f32_16x16x32_bf16(
                        bfr[nt], af[it], acc[it][nt], 0, 0, 0);
        }
        __syncthreads();
    }
    #pragma unroll
    for (int it = 0; it < 4; ++it) {
        size_t pos = posBase + i0w + it * 16 + ln15;
        #pragma unroll
        for (int nt = 0; nt < 4; ++nt) {
            int ncol0 = nb * 128 + n0w + nt * 16 + quad * 4;
            const float4 fbv = *(const float4*)&fb[ncol0];
            float4 o;
            o.x = acc[it][nt][0] + fbv.x;
            o.y = acc[it][nt][1] + fbv.y;
            o.z = acc[it][nt][2] + fbv.z;
            o.w = acc[it][nt][3] + fbv.w;
            *(float4*)&out[pos * 256 + ncol0] = o;
        }
    }
}

extern "C" void kernel_launch(void* const* d_in, const int* in_sizes, int n_in,
                              void* d_out, int out_size, void* d_ws, size_t ws_size,
                              hipStream_t stream) {
    const float* x1d     = (const float*)d_in[0];
    const float* x2d     = (const float*)d_in[1];
    const float* norm_w  = (const float*)d_in[2];
    const float* norm_b  = (const float*)d_in[3];
    const float* qkv_w   = (const float*)d_in[4];
    const float* x2d_w   = (const float*)d_in[5];
    const float* gate_w  = (const float*)d_in[6];
    const float* gate_b  = (const float*)d_in[7];
    const float* final_w = (const float*)d_in[8];
    const float* final_b = (const float*)d_in[9];
    float* out = (float*)d_out;
    char* w = (char*)d_ws;

    short* Ahi   = (short*)(w + OFF_AHI);
    short* attnB = (short*)(w + OFF_ATTN);
    float* biasT = (float*)(w + OFF_BIAST);
    short* Whi   = (short*)(w + OFF_WHI);
    short* W2p   = (short*)(w + OFF_W2P);
    float* gbp   = (float*)(w + OFF_GBP);

    k_prep<<<10497, 256, 0, stream>>>(x1d, norm_w, norm_b, qkv_w, gate_w, gate_b,
                                      final_w, x2d, x2d_w, Ahi, Whi, W2p, gbp, biasT);
    k_fused<<<1024, 512, 0, stream>>>(Ahi, Whi, gbp, biasT, attnB);
    k_gemm2m<<<dim3(256, 2), 256, 0, stream>>>(attnB, W2p, final_b, out);
}